// Round 7
// baseline (381.025 us; speedup 1.0000x reference)
//
#include <hip/hip_runtime.h>

#define N_NODES 50000
#define E_EDGES 800000
#define IN_DIM  512
#define HID     256
#define OUTD    64

#define M_PAD   50048              // 391 * 128 (also 782 * 64)
#define SCAN_NB  49                // ceil(50000/1024)
#define PAD_N    (SCAN_NB * 1024)  // 50176

typedef unsigned int uint;
typedef unsigned short ushort;

using short8 = __attribute__((ext_vector_type(8))) short;
using f32x4  = __attribute__((ext_vector_type(4))) float;

__device__ __forceinline__ ushort f2bf(float f) {
    union { float f; uint u; } v; v.f = f;
    uint u = v.u;
    uint r = (u + 0x7FFFu + ((u >> 16) & 1u)) >> 16;  // RNE
    return (ushort)r;
}

__device__ __forceinline__ float bf2f(ushort h) {
    union { uint u; float f; } v; v.u = ((uint)h) << 16;
    return v.f;
}

// HW packed convert: dst = {bf16(a) | bf16(b)<<16}, RNE — 1 instr per 2 elems
__device__ __forceinline__ uint pk2(float a, float b) {
    uint r;
    asm("v_cvt_pk_bf16_f32 %0, %1, %2" : "=v"(r) : "v"(a), "v"(b));
    return r;
}

// 16B global -> LDS DMA. LDS dest is wave-uniform base + lane*16 (HW rule);
// global source is per-lane (pre-swizzled-source pattern).
__device__ __forceinline__ void gld_lds16(const ushort* g, ushort* l) {
    __builtin_amdgcn_global_load_lds(
        (const __attribute__((address_space(1))) unsigned int*)g,
        (__attribute__((address_space(3))) unsigned int*)l, 16, 0, 0);
}

// counted vmem wait: compile-time immediate only
template <int N>
__device__ __forceinline__ void wait_vmcnt() {
    static_assert(N == 0 || N == 4 || N == 6 || N == 8, "add literal");
    if constexpr (N == 0) asm volatile("s_waitcnt vmcnt(0)" ::: "memory");
    else if constexpr (N == 4) asm volatile("s_waitcnt vmcnt(4)" ::: "memory");
    else if constexpr (N == 6) asm volatile("s_waitcnt vmcnt(6)" ::: "memory");
    else if constexpr (N == 8) asm volatile("s_waitcnt vmcnt(8)" ::: "memory");
}

// ---------------------------------------------------------------- converts
// x [N,512] fp32 -> bf16, 8 elems/thread (RNE identical to in-GEMM convert)
__global__ __launch_bounds__(256) void cvt_x_k(const float* __restrict__ x,
                                               ushort* __restrict__ xb) {
    int i = blockIdx.x * 256 + threadIdx.x;
    const int total = N_NODES * IN_DIM / 8;  // 3.2M
    if (i < total) {
        const float* p = x + (size_t)i * 8;
        float4 f0 = *(const float4*)p;
        float4 f1 = *(const float4*)(p + 4);
        uint4 q;
        q.x = pk2(f0.x, f0.y);
        q.y = pk2(f0.z, f0.w);
        q.z = pk2(f1.x, f1.y);
        q.w = pk2(f1.z, f1.w);
        *(uint4*)(xb + (size_t)i * 8) = q;
    }
}

// fused: zero cnt[] + transpose/convert W1,W2 -> bf16 [N,K] (independent work)
__global__ __launch_bounds__(256) void init_k(const float* __restrict__ W1,
                                              const float* __restrict__ W2,
                                              ushort* __restrict__ W1t,
                                              ushort* __restrict__ W2t,
                                              int* __restrict__ cnt) {
    int i = blockIdx.x * 256 + threadIdx.x;
    if (i < PAD_N) cnt[i] = 0;
    const int N1 = IN_DIM * HID;  // 131072
    if (i < N1) {
        int n = i / IN_DIM;
        int k = i - n * IN_DIM;
        W1t[i] = f2bf(W1[(size_t)k * HID + n]);
    } else {
        int j = i - N1;
        if (j < HID * OUTD) {
            int n = j / HID;
            int k = j - n * HID;
            W2t[j] = f2bf(W2[(size_t)k * OUTD + n]);
        }
    }
}

// ---------------------------------------------------------------- CSR build
// hist + per-edge rank in one pass: rank[e] = position of edge within its row
__global__ void hist_k(const int* __restrict__ rows, int* __restrict__ cnt,
                       int* __restrict__ rank) {
    int e = blockIdx.x * 256 + threadIdx.x;
    if (e < E_EDGES) rank[e] = atomicAdd(&cnt[rows[e]], 1);
}

__global__ __launch_bounds__(256) void scan_part_k(const int* __restrict__ cnt,
                                                   int* __restrict__ bsum) {
    __shared__ int wsum[4];
    int tid  = threadIdx.x;
    int lane = tid & 63;
    int wave = tid >> 6;
    int4 q = *(const int4*)(cnt + blockIdx.x * 1024 + tid * 4);
    int s = q.x + q.y + q.z + q.w;
    #pragma unroll
    for (int d = 32; d > 0; d >>= 1) s += __shfl_down(s, d, 64);
    if (lane == 0) wsum[wave] = s;
    __syncthreads();
    if (tid == 0) bsum[blockIdx.x] = wsum[0] + wsum[1] + wsum[2] + wsum[3];
}

__global__ __launch_bounds__(64) void scan_bsum_k(const int* __restrict__ bsum,
                                                  int* __restrict__ boff) {
    int tid = threadIdx.x;
    int v = (tid < SCAN_NB) ? bsum[tid] : 0;
    int incl = v;
    #pragma unroll
    for (int d = 1; d < 64; d <<= 1) {
        int t = __shfl_up(incl, d, 64);
        if (tid >= d) incl += t;
    }
    if (tid < SCAN_NB) boff[tid] = incl - v;
}

__global__ __launch_bounds__(256) void scan_final_k(const int* __restrict__ cnt,
                                                    const int* __restrict__ boff,
                                                    int* __restrict__ row_ptr) {
    __shared__ int wsum[4];
    __shared__ int woff[4];
    int tid  = threadIdx.x;
    int lane = tid & 63;
    int wave = tid >> 6;
    int base = blockIdx.x * 1024 + tid * 4;
    int4 q = *(const int4*)(cnt + base);
    int s = q.x + q.y + q.z + q.w;
    int incl = s;
    #pragma unroll
    for (int d = 1; d < 64; d <<= 1) {
        int t = __shfl_up(incl, d, 64);
        if (lane >= d) incl += t;
    }
    if (lane == 63) wsum[wave] = incl;
    __syncthreads();
    if (tid == 0) {
        int run = 0;
        #pragma unroll
        for (int w = 0; w < 4; w++) { woff[w] = run; run += wsum[w]; }
    }
    __syncthreads();
    int off = boff[blockIdx.x] + woff[wave] + (incl - s);
    int4 o;
    o.x = off;
    o.y = off + q.x;
    o.z = o.y + q.y;
    o.w = o.z + q.z;
    *(int4*)(row_ptr + base) = o;
    if (blockIdx.x == 0 && tid == 0) row_ptr[N_NODES] = E_EDGES;
}

// atomic-free scatter: slot = row_ptr[row] + precomputed rank
__global__ void scatter_k(const int* __restrict__ rows, const int* __restrict__ cols,
                          const float* __restrict__ vals, const int* __restrict__ rptr,
                          const int* __restrict__ rank,
                          int* __restrict__ col_s, float* __restrict__ val_s) {
    int e = blockIdx.x * 256 + threadIdx.x;
    if (e < E_EDGES) {
        int p = rptr[rows[e]] + rank[e];
        col_s[p] = cols[e];
        val_s[p] = vals[e];
    }
}

// ---------------------------------------------------------------- GEMM ring
// C[M,N](bf16) = A[M,K](bf16) * Bt[N,K](bf16). All-DMA staging, 3-slot LDS
// ring, prefetch distance 2, COUNTED vmcnt (T3/T4): loads stay in flight
// ACROSS barriers — the r0/r5/r6 structures all drained vmcnt(0) per iter
// and pinned at ~60us / 2 TB/s.
// Per-wave FIFO accounting (IPW = (BM+BN)/32 DMA issues per wave per stage):
//   prologue: issue S0,S1; vmcnt(IPW) -> S0 done; barrier.
//   iter k:   issue S(k+2) into slot (k+2)%3 (retired at barrier of k-1);
//             compute S(k); vmcnt(IPW) -> S(k+1) done; raw s_barrier.
//   tail:     vmcnt(0) when no more issues; no barrier after last compute.
// Both-sides XOR swizzle (verified r5/r6): store source col-group
// (lane&7)^((lane>>3)&7); read col slot (((kk>>3)+quad)^(row&7)).
// A must have >= gridY*BM rows allocated (M_PAD) — garbage pad rows only
// affect never-stored C rows (MFMA D-row independence).
template <int BM, int BN, int RW, int CW, int WM, int WN>
__global__ __launch_bounds__(256) void gemm_ring(const ushort* __restrict__ A,
                                                 const ushort* __restrict__ Bt,
                                                 ushort* __restrict__ C,
                                                 int M, int N, int K) {
    constexpr int BK   = 64;
    constexpr int SLOT = (BM + BN) * BK;       // ushorts per ring slot
    constexpr int IPW  = (BM + BN) / 32;       // DMA issues per wave per stage
    __shared__ ushort L[3 * SLOT];

    const int tid  = threadIdx.x;
    const int lane = tid & 63;
    const int wave = tid >> 6;
    const int quad = lane >> 4;
    const int l15  = lane & 15;
    const int l7   = lane & 7;

    const int col0 = blockIdx.x * BN;
    const int row0 = blockIdx.y * BM;

    const int wr = (wave % RW) * (WM * 16);
    const int wc = (wave / RW) * (WN * 16);

    const int swz    = (l7 ^ ((lane >> 3) & 7)) << 3;  // source col offset (ushorts)
    const int subrow = lane >> 3;                      // row within 8-row chunk

    f32x4 acc[WM][WN] = {};

#define ISSUE(SIDX, KOFF)                                                     \
    {                                                                         \
        ushort* Aw = L + (SIDX) * SLOT;                                       \
        ushort* Bw = Aw + BM * BK;                                            \
        _Pragma("unroll")                                                     \
        for (int p = 0; p < BM / 32; p++) {                                   \
            int ch  = wave * (BM / 32) + p;                                   \
            int row = ch * 8 + subrow;                                        \
            gld_lds16(A + (size_t)(row0 + row) * K + (KOFF) + swz,            \
                      Aw + ch * 512);                                         \
        }                                                                     \
        _Pragma("unroll")                                                     \
        for (int p = 0; p < BN / 32; p++) {                                   \
            int ch  = wave * (BN / 32) + p;                                   \
            int row = ch * 8 + subrow;                                        \
            gld_lds16(Bt + (size_t)(col0 + row) * K + (KOFF) + swz,           \
                      Bw + ch * 512);                                         \
        }                                                                     \
    }

#define COMPUTE(SIDX)                                                         \
    {                                                                         \
        const ushort* Ar = L + (SIDX) * SLOT;                                 \
        const ushort* Br = Ar + BM * BK;                                      \
        _Pragma("unroll")                                                     \
        for (int kk = 0; kk < BK; kk += 32) {                                 \
            const int sg = ((((kk >> 3) + quad) ^ l7) << 3);                  \
            short8 af[WM], bf[WN];                                            \
            _Pragma("unroll")                                                 \
            for (int i = 0; i < WM; i++)                                      \
                af[i] = *(const short8*)&Ar[(wr + i * 16 + l15) * 64 + sg];   \
            _Pragma("unroll")                                                 \
            for (int j = 0; j < WN; j++)                                      \
                bf[j] = *(const short8*)&Br[(wc + j * 16 + l15) * 64 + sg];   \
            _Pragma("unroll")                                                 \
            for (int i = 0; i < WM; i++)                                      \
                _Pragma("unroll")                                             \
                for (int j = 0; j < WN; j++)                                  \
                    acc[i][j] = __builtin_amdgcn_mfma_f32_16x16x32_bf16(af[i], bf[j], acc[i][j], 0, 0, 0); \
        }                                                                     \
    }

    const int NITER = K / BK;   // >= 4 for both layers

    // prologue: two stages in flight, wait for the first only
    ISSUE(0, 0)
    ISSUE(1, BK)
    wait_vmcnt<IPW>();
    __builtin_amdgcn_s_barrier();
    __builtin_amdgcn_sched_barrier(0);

    int c = 0;  // compute slot
    for (int k = 0; k < NITER; k++) {
        int isl = c + 2; if (isl >= 3) isl -= 3;
        if (k + 2 < NITER) ISSUE(isl, (k + 2) * BK)
        COMPUTE(c)
        if (k + 1 < NITER) {
            if (k + 2 < NITER) wait_vmcnt<IPW>();   // S(k+1) done, S(k+2) in flight
            else               wait_vmcnt<0>();     // tail drain
            __builtin_amdgcn_s_barrier();
            __builtin_amdgcn_sched_barrier(0);
        }
        c = c + 1; if (c >= 3) c -= 3;
    }

#undef ISSUE
#undef COMPUTE

    // epilogue: C/D layout col=lane&15, row=quad*4+reg
    #pragma unroll
    for (int i = 0; i < WM; i++)
        #pragma unroll
        for (int j = 0; j < WN; j++)
            #pragma unroll
            for (int rr = 0; rr < 4; rr++) {
                int grow = row0 + wr + i * 16 + quad * 4 + rr;
                int gcol = col0 + wc + j * 16 + l15;
                if (grow < M) C[(size_t)grow * N + gcol] = f2bf(acc[i][j][rr]);
            }
}

// ---------------------------------------------------------------- SpMM 1
// wave per row; lane covers dims [lane*4, lane*4+4). Edge loop unrolled x4:
// 4 independent 512B gathers in flight to break the latency chain.
__global__ __launch_bounds__(256) void spmm1_k(const int* __restrict__ row_ptr,
                                               const int* __restrict__ col_s,
                                               const float* __restrict__ val_s,
                                               const ushort* __restrict__ h0,
                                               const float* __restrict__ b1,
                                               ushort* __restrict__ h) {
    int wave = threadIdx.x >> 6;
    int lane = threadIdx.x & 63;
    int r = blockIdx.x * 4 + wave;
    if (r >= N_NODES) return;
    int s = row_ptr[r];
    int e = row_ptr[r + 1];
    const ushort* hp = h0 + (size_t)lane * 4;
    float a0 = 0.f, a1 = 0.f, a2 = 0.f, a3 = 0.f;
    int i = s;
    for (; i + 4 <= e; i += 4) {
        int c0 = col_s[i];
        int c1 = col_s[i + 1];
        int c2 = col_s[i + 2];
        int c3 = col_s[i + 3];
        float v0 = val_s[i];
        float v1 = val_s[i + 1];
        float v2 = val_s[i + 2];
        float v3 = val_s[i + 3];
        ushort4 q0 = *(const ushort4*)(hp + (size_t)c0 * HID);
        ushort4 q1 = *(const ushort4*)(hp + (size_t)c1 * HID);
        ushort4 q2 = *(const ushort4*)(hp + (size_t)c2 * HID);
        ushort4 q3 = *(const ushort4*)(hp + (size_t)c3 * HID);
        a0 += v0 * bf2f(q0.x); a1 += v0 * bf2f(q0.y); a2 += v0 * bf2f(q0.z); a3 += v0 * bf2f(q0.w);
        a0 += v1 * bf2f(q1.x); a1 += v1 * bf2f(q1.y); a2 += v1 * bf2f(q1.z); a3 += v1 * bf2f(q1.w);
        a0 += v2 * bf2f(q2.x); a1 += v2 * bf2f(q2.y); a2 += v2 * bf2f(q2.z); a3 += v2 * bf2f(q2.w);
        a0 += v3 * bf2f(q3.x); a1 += v3 * bf2f(q3.y); a2 += v3 * bf2f(q3.z); a3 += v3 * bf2f(q3.w);
    }
    for (; i < e; i++) {
        int c = col_s[i];
        float v = val_s[i];
        ushort4 q = *(const ushort4*)(hp + (size_t)c * HID);
        a0 += v * bf2f(q.x); a1 += v * bf2f(q.y); a2 += v * bf2f(q.z); a3 += v * bf2f(q.w);
    }
    float4 bb = *(const float4*)(b1 + lane * 4);
    a0 += bb.x; a1 += bb.y; a2 += bb.z; a3 += bb.w;
    a0 = fmaxf(a0, 0.f); a1 = fmaxf(a1, 0.f); a2 = fmaxf(a2, 0.f); a3 = fmaxf(a3, 0.f);
    ushort4 o;
    o.x = f2bf(a0); o.y = f2bf(a1); o.z = f2bf(a2); o.w = f2bf(a3);
    *(ushort4*)(h + (size_t)r * HID + lane * 4) = o;
}

// ---------------------------------------------------------------- SpMM 2
__global__ __launch_bounds__(256) void spmm2_k(const int* __restrict__ row_ptr,
                                               const int* __restrict__ col_s,
                                               const float* __restrict__ val_s,
                                               const ushort* __restrict__ h2,
                                               const float* __restrict__ b2,
                                               float* __restrict__ out) {
    int wave = threadIdx.x >> 6;
    int lane = threadIdx.x & 63;
    int r = blockIdx.x * 4 + wave;
    if (r >= N_NODES) return;
    int s = row_ptr[r];
    int e = row_ptr[r + 1];
    int slot = lane >> 4;   // 0..3
    int dg   = lane & 15;   // dim group, 4 dims
    float a0 = 0.f, a1 = 0.f, a2 = 0.f, a3 = 0.f;
    const ushort* hp = h2 + (size_t)dg * 4;
    for (int i = s + slot; i < e; i += 4) {
        int c = col_s[i];
        float v = val_s[i];
        ushort4 q = *(const ushort4*)(hp + (size_t)c * OUTD);
        a0 += v * bf2f(q.x);
        a1 += v * bf2f(q.y);
        a2 += v * bf2f(q.z);
        a3 += v * bf2f(q.w);
    }
    #pragma unroll
    for (int m = 16; m < 64; m <<= 1) {
        a0 += __shfl_xor(a0, m, 64);
        a1 += __shfl_xor(a1, m, 64);
        a2 += __shfl_xor(a2, m, 64);
        a3 += __shfl_xor(a3, m, 64);
    }
    if (slot == 0) {
        float4 bb = *(const float4*)(b2 + dg * 4);
        float4 o;
        o.x = a0 + bb.x; o.y = a1 + bb.y; o.z = a2 + bb.z; o.w = a3 + bb.w;
        *(float4*)(out + (size_t)r * OUTD + dg * 4) = o;
    }
}

// ---------------------------------------------------------------- launch
extern "C" void kernel_launch(void* const* d_in, const int* in_sizes, int n_in,
                              void* d_out, int out_size, void* d_ws, size_t ws_size,
                              hipStream_t stream) {
    const float* x    = (const float*)d_in[0];
    const int*   rows = (const int*)d_in[1];
    const int*   cols = (const int*)d_in[2];
    const float* vals = (const float*)d_in[3];
    const float* W1   = (const float*)d_in[4];
    const float* b1   = (const float*)d_in[5];
    const float* W2   = (const float*)d_in[6];
    const float* b2   = (const float*)d_in[7];
    float* out = (float*)d_out;

    char* ws = (char*)d_ws;
    size_t off = 0;
    auto alloc = [&](size_t bytes) {
        char* p = ws + off;
        off = (off + bytes + 255) & ~(size_t)255;
        return p;
    };
    ushort* w1t   = (ushort*)alloc((size_t)HID * IN_DIM * 2);
    ushort* w2t   = (ushort*)alloc((size_t)OUTD * HID * 2);
    ushort* xb    = (ushort*)alloc((size_t)M_PAD * IN_DIM * 2);  // x in bf16, padded rows
    ushort* h0    = (ushort*)alloc((size_t)N_NODES * HID * 2);
    ushort* h     = (ushort*)alloc((size_t)M_PAD * HID * 2);     // padded rows
    ushort* h2    = (ushort*)alloc((size_t)N_NODES * OUTD * 2);
    int*    cnt   = (int*)alloc((PAD_N) * 4);
    int*    rptr  = (int*)alloc((PAD_N + 1) * 4);
    int*    bsum  = (int*)alloc(SCAN_NB * 4);
    int*    boff  = (int*)alloc(SCAN_NB * 4);
    int*    rank  = (int*)alloc((size_t)E_EDGES * 4);
    int*    col_s = (int*)alloc((size_t)E_EDGES * 4);
    float*  val_s = (float*)alloc((size_t)E_EDGES * 4);

    // init: zero cnt + weight transpose/convert (fused, independent work)
    {
        const int work = IN_DIM * HID + HID * OUTD;  // 147456 > PAD_N
        init_k<<<(work + 255) / 256, 256, 0, stream>>>(W1, W2, w1t, w2t, cnt);
    }
    // x -> bf16 (also leaves xb hot in L2/L3 for the GEMM)
    cvt_x_k<<<(N_NODES * IN_DIM / 8 + 255) / 256, 256, 0, stream>>>(x, xb);

    // CSR build (reused by both SpMMs)
    hist_k<<<(E_EDGES + 255) / 256, 256, 0, stream>>>(rows, cnt, rank);
    scan_part_k<<<SCAN_NB, 256, 0, stream>>>(cnt, bsum);
    scan_bsum_k<<<1, 64, 0, stream>>>(bsum, boff);
    scan_final_k<<<SCAN_NB, 256, 0, stream>>>(cnt, boff, rptr);
    scatter_k<<<(E_EDGES + 255) / 256, 256, 0, stream>>>(rows, cols, vals, rptr, rank, col_s, val_s);

    // layer 1: h0 = xb @ W1. 64x64 tiles, ring pipeline; grid 4 x 782
    gemm_ring<64, 64, 2, 2, 2, 2><<<dim3(HID / 64, M_PAD / 64), 256, 0, stream>>>(
        xb, w1t, h0, N_NODES, HID, IN_DIM);
    spmm1_k<<<(N_NODES + 3) / 4, 256, 0, stream>>>(rptr, col_s, val_s, h0, b1, h);

    // layer 2: same ring kernel; grid 1 x 782
    gemm_ring<64, 64, 2, 2, 2, 2><<<dim3(OUTD / 64, M_PAD / 64), 256, 0, stream>>>(
        h, w2t, h2, N_NODES, OUTD, HID);
    spmm2_k<<<(N_NODES + 3) / 4, 256, 0, stream>>>(rptr, col_s, val_s, h2, b2, out);
}

// Round 8
// 356.443 us; speedup vs baseline: 1.0690x; 1.0690x over previous
//
#include <hip/hip_runtime.h>

#define N_NODES 50000
#define E_EDGES 800000
#define IN_DIM  512
#define HID     256
#define OUTD    64

#define MP_BIG  50176              // 196 * 256 rows (fat-tile GEMM grid)
#define SCAN_NB  49                // ceil(50000/1024)
#define PAD_N    (SCAN_NB * 1024)  // 50176

typedef unsigned int uint;
typedef unsigned short ushort;

using short8 = __attribute__((ext_vector_type(8))) short;
using f32x4  = __attribute__((ext_vector_type(4))) float;

__device__ __forceinline__ ushort f2bf(float f) {
    union { float f; uint u; } v; v.f = f;
    uint u = v.u;
    uint r = (u + 0x7FFFu + ((u >> 16) & 1u)) >> 16;  // RNE
    return (ushort)r;
}

__device__ __forceinline__ float bf2f(ushort h) {
    union { uint u; float f; } v; v.u = ((uint)h) << 16;
    return v.f;
}

// HW packed convert: dst = {bf16(a) | bf16(b)<<16}, RNE — 1 instr per 2 elems
__device__ __forceinline__ uint pk2(float a, float b) {
    uint r;
    asm("v_cvt_pk_bf16_f32 %0, %1, %2" : "=v"(r) : "v"(a), "v"(b));
    return r;
}

// 16B global -> LDS DMA. LDS dest is wave-uniform base + lane*16 (HW rule);
// global source is per-lane (pre-swizzled-source pattern).
__device__ __forceinline__ void gld_lds16(const ushort* g, ushort* l) {
    __builtin_amdgcn_global_load_lds(
        (const __attribute__((address_space(1))) unsigned int*)g,
        (__attribute__((address_space(3))) unsigned int*)l, 16, 0, 0);
}

// ---------------------------------------------------------------- init
// fused: zero cnt[] + transpose/convert W1,W2 -> bf16 [N,K] (independent work)
__global__ __launch_bounds__(256) void init_k(const float* __restrict__ W1,
                                              const float* __restrict__ W2,
                                              ushort* __restrict__ W1t,
                                              ushort* __restrict__ W2t,
                                              int* __restrict__ cnt) {
    int i = blockIdx.x * 256 + threadIdx.x;
    if (i < PAD_N) cnt[i] = 0;
    const int N1 = IN_DIM * HID;  // 131072
    if (i < N1) {
        int n = i / IN_DIM;
        int k = i - n * IN_DIM;
        W1t[i] = f2bf(W1[(size_t)k * HID + n]);
    } else {
        int j = i - N1;
        if (j < HID * OUTD) {
            int n = j / HID;
            int k = j - n * HID;
            W2t[j] = f2bf(W2[(size_t)k * OUTD + n]);
        }
    }
}

// ---------------------------------------------------------------- CSR build
// hist + per-edge rank in one pass: rank[e] = position of edge within its row
__global__ void hist_k(const int* __restrict__ rows, int* __restrict__ cnt,
                       int* __restrict__ rank) {
    int e = blockIdx.x * 256 + threadIdx.x;
    if (e < E_EDGES) rank[e] = atomicAdd(&cnt[rows[e]], 1);
}

__global__ __launch_bounds__(256) void scan_part_k(const int* __restrict__ cnt,
                                                   int* __restrict__ bsum) {
    __shared__ int wsum[4];
    int tid  = threadIdx.x;
    int lane = tid & 63;
    int wave = tid >> 6;
    int4 q = *(const int4*)(cnt + blockIdx.x * 1024 + tid * 4);
    int s = q.x + q.y + q.z + q.w;
    #pragma unroll
    for (int d = 32; d > 0; d >>= 1) s += __shfl_down(s, d, 64);
    if (lane == 0) wsum[wave] = s;
    __syncthreads();
    if (tid == 0) bsum[blockIdx.x] = wsum[0] + wsum[1] + wsum[2] + wsum[3];
}

__global__ __launch_bounds__(64) void scan_bsum_k(const int* __restrict__ bsum,
                                                  int* __restrict__ boff) {
    int tid = threadIdx.x;
    int v = (tid < SCAN_NB) ? bsum[tid] : 0;
    int incl = v;
    #pragma unroll
    for (int d = 1; d < 64; d <<= 1) {
        int t = __shfl_up(incl, d, 64);
        if (tid >= d) incl += t;
    }
    if (tid < SCAN_NB) boff[tid] = incl - v;
}

__global__ __launch_bounds__(256) void scan_final_k(const int* __restrict__ cnt,
                                                    const int* __restrict__ boff,
                                                    int* __restrict__ row_ptr) {
    __shared__ int wsum[4];
    __shared__ int woff[4];
    int tid  = threadIdx.x;
    int lane = tid & 63;
    int wave = tid >> 6;
    int base = blockIdx.x * 1024 + tid * 4;
    int4 q = *(const int4*)(cnt + base);
    int s = q.x + q.y + q.z + q.w;
    int incl = s;
    #pragma unroll
    for (int d = 1; d < 64; d <<= 1) {
        int t = __shfl_up(incl, d, 64);
        if (lane >= d) incl += t;
    }
    if (lane == 63) wsum[wave] = incl;
    __syncthreads();
    if (tid == 0) {
        int run = 0;
        #pragma unroll
        for (int w = 0; w < 4; w++) { woff[w] = run; run += wsum[w]; }
    }
    __syncthreads();
    int off = boff[blockIdx.x] + woff[wave] + (incl - s);
    int4 o;
    o.x = off;
    o.y = off + q.x;
    o.z = o.y + q.y;
    o.w = o.z + q.z;
    *(int4*)(row_ptr + base) = o;
    if (blockIdx.x == 0 && tid == 0) row_ptr[N_NODES] = E_EDGES;
}

// atomic-free scatter: slot = row_ptr[row] + precomputed rank
__global__ void scatter_k(const int* __restrict__ rows, const int* __restrict__ cols,
                          const float* __restrict__ vals, const int* __restrict__ rptr,
                          const int* __restrict__ rank,
                          int* __restrict__ col_s, float* __restrict__ val_s) {
    int e = blockIdx.x * 256 + threadIdx.x;
    if (e < E_EDGES) {
        int p = rptr[rows[e]] + rank[e];
        col_s[p] = cols[e];
        val_s[p] = vals[e];
    }
}

// ---------------------------------------------------------------- GEMM fat-M
// C[M,N](bf16) = A[M,K] * Bt[N,K](bf16). BYTES model (r0-r7 retrofit): the
// GEMM runs at the vector-load pipe ceiling (~10 B/cyc/CU, ~6 TB/s chip) on
// TOTAL STAGED BYTES; schedule variants were all neutral. So: minimize bytes.
// BM=256 -> grid 196 blocks (1/CU): B staged 196x, not 782-3128x.
//   L1: A(fp32) 102 MB + B 50 MB = 152 MB  (was 300-400 MB)
//   L2: A 25 MB + B 6 MB                    (was ~50 MB)
// 512 threads / 8 waves so acc = WM*WN*4 <= 128 VGPR. Single LDS buffer,
// 2-barrier loop (proven). A fp32 staged via register cvt_pk into padded-72
// rows; bf16 tiles via DMA with both-sides XOR swizzle (verified r5-r7):
//   store: source col-group (lane&7)^((lane>>3)&7)
//   read:  col slot (((kk>>3)+quad)^(lane&7))
template <bool AF32, int BM, int BN, int RW, int CW, int WM, int WN>
__global__ __launch_bounds__(512) void gemm_big(const float* __restrict__ Af,
                                                const ushort* __restrict__ Ab,
                                                const ushort* __restrict__ Bt,
                                                ushort* __restrict__ C,
                                                int M, int N, int K) {
    constexpr int BK   = 64;
    constexpr int LDTA = AF32 ? 72 : 64;        // A rows: padded (reg) / linear (DMA)
    constexpr int ACH  = (BM * BK / 8) / 512;   // fp32 path chunks per thread (4)
    __shared__ ushort As[BM * LDTA];
    __shared__ ushort Bs[BN * 64];

    const int tid  = threadIdx.x;
    const int lane = tid & 63;
    const int wave = tid >> 6;       // 0..7
    const int quad = lane >> 4;
    const int l15  = lane & 15;
    const int l7   = lane & 7;

    const int col0 = blockIdx.x * BN;
    const int row0 = blockIdx.y * BM;

    const int wr = (wave % RW) * (WM * 16);
    const int wc = (wave / RW) * (WN * 16);

    const int swz    = (l7 ^ ((lane >> 3) & 7)) << 3;  // DMA source col offset
    const int subrow = lane >> 3;                      // row within 8-row chunk

    f32x4 acc[WM][WN] = {};

    for (int k0 = 0; k0 < K; k0 += BK) {
        // ---- A tile
        if constexpr (AF32) {
            #pragma unroll
            for (int p = 0; p < ACH; p++) {
                int c = tid + p * 512;
                int row = c >> 3, sub = c & 7;
                int gr = row0 + row;
                gr = gr < M ? gr : M - 1;          // x has exactly M rows
                const float* pa = Af + (size_t)gr * K + k0 + sub * 8;
                float4 f0 = *(const float4*)pa;
                float4 f1 = *(const float4*)(pa + 4);
                uint4 q;
                q.x = pk2(f0.x, f0.y);
                q.y = pk2(f0.z, f0.w);
                q.z = pk2(f1.x, f1.y);
                q.w = pk2(f1.z, f1.w);
                *(uint4*)&As[row * LDTA + sub * 8] = q;
            }
        } else {
            // A buffer padded to gridY*BM rows: always in-bounds
            #pragma unroll
            for (int p = 0; p < BM / 64; p++) {
                int ch  = wave * (BM / 64) + p;
                int row = ch * 8 + subrow;
                gld_lds16(Ab + (size_t)(row0 + row) * K + k0 + swz, &As[ch * 512]);
            }
        }
        // ---- B tile: DMA, fire-and-forget until barrier's vmcnt drain
        #pragma unroll
        for (int p = 0; p < BN / 64; p++) {
            int ch  = wave * (BN / 64) + p;
            int row = ch * 8 + subrow;
            gld_lds16(Bt + (size_t)(col0 + row) * K + k0 + swz, &Bs[ch * 512]);
        }
        __syncthreads();
        #pragma unroll
        for (int kk = 0; kk < BK; kk += 32) {
            const int sg = ((((kk >> 3) + quad) ^ l7) << 3);  // swizzled read col
            short8 af[WM], bf[WN];
            #pragma unroll
            for (int i = 0; i < WM; i++) {
                int row = wr + i * 16 + l15;
                af[i] = AF32 ? *(const short8*)&As[row * LDTA + kk + quad * 8]
                             : *(const short8*)&As[row * 64 + sg];
            }
            #pragma unroll
            for (int j = 0; j < WN; j++) {
                int row = wc + j * 16 + l15;
                bf[j] = *(const short8*)&Bs[row * 64 + sg];
            }
            #pragma unroll
            for (int i = 0; i < WM; i++)
                #pragma unroll
                for (int j = 0; j < WN; j++)
                    acc[i][j] = __builtin_amdgcn_mfma_f32_16x16x32_bf16(af[i], bf[j], acc[i][j], 0, 0, 0);
        }
        __syncthreads();
    }

    // epilogue: C/D layout col=lane&15, row=quad*4+reg
    #pragma unroll
    for (int i = 0; i < WM; i++)
        #pragma unroll
        for (int j = 0; j < WN; j++)
            #pragma unroll
            for (int rr = 0; rr < 4; rr++) {
                int grow = row0 + wr + i * 16 + quad * 4 + rr;
                int gcol = col0 + wc + j * 16 + l15;
                if (grow < M) C[(size_t)grow * N + gcol] = f2bf(acc[i][j][rr]);
            }
}

// ---------------------------------------------------------------- SpMM 1
// wave per row; lane covers dims [lane*4, lane*4+4). Edge loop unrolled x4:
// 4 independent 512B gathers in flight to break the latency chain.
__global__ __launch_bounds__(256) void spmm1_k(const int* __restrict__ row_ptr,
                                               const int* __restrict__ col_s,
                                               const float* __restrict__ val_s,
                                               const ushort* __restrict__ h0,
                                               const float* __restrict__ b1,
                                               ushort* __restrict__ h) {
    int wave = threadIdx.x >> 6;
    int lane = threadIdx.x & 63;
    int r = blockIdx.x * 4 + wave;
    if (r >= N_NODES) return;
    int s = row_ptr[r];
    int e = row_ptr[r + 1];
    const ushort* hp = h0 + (size_t)lane * 4;
    float a0 = 0.f, a1 = 0.f, a2 = 0.f, a3 = 0.f;
    int i = s;
    for (; i + 4 <= e; i += 4) {
        int c0 = col_s[i];
        int c1 = col_s[i + 1];
        int c2 = col_s[i + 2];
        int c3 = col_s[i + 3];
        float v0 = val_s[i];
        float v1 = val_s[i + 1];
        float v2 = val_s[i + 2];
        float v3 = val_s[i + 3];
        ushort4 q0 = *(const ushort4*)(hp + (size_t)c0 * HID);
        ushort4 q1 = *(const ushort4*)(hp + (size_t)c1 * HID);
        ushort4 q2 = *(const ushort4*)(hp + (size_t)c2 * HID);
        ushort4 q3 = *(const ushort4*)(hp + (size_t)c3 * HID);
        a0 += v0 * bf2f(q0.x); a1 += v0 * bf2f(q0.y); a2 += v0 * bf2f(q0.z); a3 += v0 * bf2f(q0.w);
        a0 += v1 * bf2f(q1.x); a1 += v1 * bf2f(q1.y); a2 += v1 * bf2f(q1.z); a3 += v1 * bf2f(q1.w);
        a0 += v2 * bf2f(q2.x); a1 += v2 * bf2f(q2.y); a2 += v2 * bf2f(q2.z); a3 += v2 * bf2f(q2.w);
        a0 += v3 * bf2f(q3.x); a1 += v3 * bf2f(q3.y); a2 += v3 * bf2f(q3.z); a3 += v3 * bf2f(q3.w);
    }
    for (; i < e; i++) {
        int c = col_s[i];
        float v = val_s[i];
        ushort4 q = *(const ushort4*)(hp + (size_t)c * HID);
        a0 += v * bf2f(q.x); a1 += v * bf2f(q.y); a2 += v * bf2f(q.z); a3 += v * bf2f(q.w);
    }
    float4 bb = *(const float4*)(b1 + lane * 4);
    a0 += bb.x; a1 += bb.y; a2 += bb.z; a3 += bb.w;
    a0 = fmaxf(a0, 0.f); a1 = fmaxf(a1, 0.f); a2 = fmaxf(a2, 0.f); a3 = fmaxf(a3, 0.f);
    ushort4 o;
    o.x = f2bf(a0); o.y = f2bf(a1); o.z = f2bf(a2); o.w = f2bf(a3);
    *(ushort4*)(h + (size_t)r * HID + lane * 4) = o;
}

// ---------------------------------------------------------------- SpMM 2
__global__ __launch_bounds__(256) void spmm2_k(const int* __restrict__ row_ptr,
                                               const int* __restrict__ col_s,
                                               const float* __restrict__ val_s,
                                               const ushort* __restrict__ h2,
                                               const float* __restrict__ b2,
                                               float* __restrict__ out) {
    int wave = threadIdx.x >> 6;
    int lane = threadIdx.x & 63;
    int r = blockIdx.x * 4 + wave;
    if (r >= N_NODES) return;
    int s = row_ptr[r];
    int e = row_ptr[r + 1];
    int slot = lane >> 4;   // 0..3
    int dg   = lane & 15;   // dim group, 4 dims
    float a0 = 0.f, a1 = 0.f, a2 = 0.f, a3 = 0.f;
    const ushort* hp = h2 + (size_t)dg * 4;
    for (int i = s + slot; i < e; i += 4) {
        int c = col_s[i];
        float v = val_s[i];
        ushort4 q = *(const ushort4*)(hp + (size_t)c * OUTD);
        a0 += v * bf2f(q.x);
        a1 += v * bf2f(q.y);
        a2 += v * bf2f(q.z);
        a3 += v * bf2f(q.w);
    }
    #pragma unroll
    for (int m = 16; m < 64; m <<= 1) {
        a0 += __shfl_xor(a0, m, 64);
        a1 += __shfl_xor(a1, m, 64);
        a2 += __shfl_xor(a2, m, 64);
        a3 += __shfl_xor(a3, m, 64);
    }
    if (slot == 0) {
        float4 bb = *(const float4*)(b2 + dg * 4);
        float4 o;
        o.x = a0 + bb.x; o.y = a1 + bb.y; o.z = a2 + bb.z; o.w = a3 + bb.w;
        *(float4*)(out + (size_t)r * OUTD + dg * 4) = o;
    }
}

// ---------------------------------------------------------------- launch
extern "C" void kernel_launch(void* const* d_in, const int* in_sizes, int n_in,
                              void* d_out, int out_size, void* d_ws, size_t ws_size,
                              hipStream_t stream) {
    const float* x    = (const float*)d_in[0];
    const int*   rows = (const int*)d_in[1];
    const int*   cols = (const int*)d_in[2];
    const float* vals = (const float*)d_in[3];
    const float* W1   = (const float*)d_in[4];
    const float* b1   = (const float*)d_in[5];
    const float* W2   = (const float*)d_in[6];
    const float* b2   = (const float*)d_in[7];
    float* out = (float*)d_out;

    char* ws = (char*)d_ws;
    size_t off = 0;
    auto alloc = [&](size_t bytes) {
        char* p = ws + off;
        off = (off + bytes + 255) & ~(size_t)255;
        return p;
    };
    ushort* w1t   = (ushort*)alloc((size_t)HID * IN_DIM * 2);
    ushort* w2t   = (ushort*)alloc((size_t)OUTD * HID * 2);
    ushort* h0    = (ushort*)alloc((size_t)N_NODES * HID * 2);
    ushort* h     = (ushort*)alloc((size_t)MP_BIG * HID * 2);    // padded rows (DMA in-bounds)
    ushort* h2    = (ushort*)alloc((size_t)N_NODES * OUTD * 2);
    int*    cnt   = (int*)alloc((PAD_N) * 4);
    int*    rptr  = (int*)alloc((PAD_N + 1) * 4);
    int*    bsum  = (int*)alloc(SCAN_NB * 4);
    int*    boff  = (int*)alloc(SCAN_NB * 4);
    int*    rank  = (int*)alloc((size_t)E_EDGES * 4);
    int*    col_s = (int*)alloc((size_t)E_EDGES * 4);
    float*  val_s = (float*)alloc((size_t)E_EDGES * 4);

    // init: zero cnt + weight transpose/convert (fused, independent work)
    {
        const int work = IN_DIM * HID + HID * OUTD;  // 147456 > PAD_N
        init_k<<<(work + 255) / 256, 256, 0, stream>>>(W1, W2, w1t, w2t, cnt);
    }
    // CSR build (reused by both SpMMs)
    hist_k<<<(E_EDGES + 255) / 256, 256, 0, stream>>>(rows, cnt, rank);
    scan_part_k<<<SCAN_NB, 256, 0, stream>>>(cnt, bsum);
    scan_bsum_k<<<1, 64, 0, stream>>>(bsum, boff);
    scan_final_k<<<SCAN_NB, 256, 0, stream>>>(cnt, boff, rptr);
    scatter_k<<<(E_EDGES + 255) / 256, 256, 0, stream>>>(rows, cols, vals, rptr, rank, col_s, val_s);

    // layer 1: h0 = x @ W1. Fat tile 256x256, grid 1x196 (1 block/CU):
    // staged bytes 152 MB (A once + B 196x) vs 300-400 MB before.
    gemm_big<true, 256, 256, 4, 2, 4, 8><<<dim3(HID / 256, MP_BIG / 256), 512, 0, stream>>>(
        x, nullptr, w1t, h0, N_NODES, HID, IN_DIM);
    spmm1_k<<<(N_NODES + 3) / 4, 256, 0, stream>>>(rptr, col_s, val_s, h0, b1, h);

    // layer 2: fat tile 256x64, all-DMA; staged 31 MB
    gemm_big<false, 256, 64, 8, 1, 2, 4><<<dim3(OUTD / 64, MP_BIG / 256), 512, 0, stream>>>(
        nullptr, h, w2t, h2, N_NODES, OUTD, HID);
    spmm2_k<<<(N_NODES + 3) / 4, 256, 0, stream>>>(rptr, col_s, val_s, h2, b2, out);
}

// Round 9
// 349.104 us; speedup vs baseline: 1.0914x; 1.0210x over previous
//
#include <hip/hip_runtime.h>

#define N_NODES 50000
#define E_EDGES 800000
#define IN_DIM  512
#define HID     256
#define OUTD    64

#define MP_BIG  50176              // 196 * 256 rows (fat-tile GEMM grid)
#define SCAN_NB  49                // ceil(50000/1024)
#define PAD_N    (SCAN_NB * 1024)  // 50176

typedef unsigned int uint;
typedef unsigned short ushort;

using short8 = __attribute__((ext_vector_type(8))) short;
using f32x4  = __attribute__((ext_vector_type(4))) float;

__device__ __forceinline__ ushort f2bf(float f) {
    union { float f; uint u; } v; v.f = f;
    uint u = v.u;
    uint r = (u + 0x7FFFu + ((u >> 16) & 1u)) >> 16;  // RNE
    return (ushort)r;
}

__device__ __forceinline__ float bf2f(ushort h) {
    union { uint u; float f; } v; v.u = ((uint)h) << 16;
    return v.f;
}

// HW packed convert: dst = {bf16(a) | bf16(b)<<16}, RNE — 1 instr per 2 elems
__device__ __forceinline__ uint pk2(float a, float b) {
    uint r;
    asm("v_cvt_pk_bf16_f32 %0, %1, %2" : "=v"(r) : "v"(a), "v"(b));
    return r;
}

// 16B global -> LDS DMA. LDS dest is wave-uniform base + lane*16 (HW rule);
// global source is per-lane (pre-swizzled-source pattern).
__device__ __forceinline__ void gld_lds16(const ushort* g, ushort* l) {
    __builtin_amdgcn_global_load_lds(
        (const __attribute__((address_space(1))) unsigned int*)g,
        (__attribute__((address_space(3))) unsigned int*)l, 16, 0, 0);
}

// ---------------------------------------------------------------- init
// fused: zero cnt[] + transpose/convert W1,W2 -> bf16 [N,K] (independent work)
__global__ __launch_bounds__(256) void init_k(const float* __restrict__ W1,
                                              const float* __restrict__ W2,
                                              ushort* __restrict__ W1t,
                                              ushort* __restrict__ W2t,
                                              int* __restrict__ cnt) {
    int i = blockIdx.x * 256 + threadIdx.x;
    if (i < PAD_N) cnt[i] = 0;
    const int N1 = IN_DIM * HID;  // 131072
    if (i < N1) {
        int n = i / IN_DIM;
        int k = i - n * IN_DIM;
        W1t[i] = f2bf(W1[(size_t)k * HID + n]);
    } else {
        int j = i - N1;
        if (j < HID * OUTD) {
            int n = j / HID;
            int k = j - n * HID;
            W2t[j] = f2bf(W2[(size_t)k * OUTD + n]);
        }
    }
}

// ---------------------------------------------------------------- CSR build
// hist + per-edge rank in one pass: rank[e] = position of edge within its row
__global__ void hist_k(const int* __restrict__ rows, int* __restrict__ cnt,
                       int* __restrict__ rank) {
    int e = blockIdx.x * 256 + threadIdx.x;
    if (e < E_EDGES) rank[e] = atomicAdd(&cnt[rows[e]], 1);
}

__global__ __launch_bounds__(256) void scan_part_k(const int* __restrict__ cnt,
                                                   int* __restrict__ bsum) {
    __shared__ int wsum[4];
    int tid  = threadIdx.x;
    int lane = tid & 63;
    int wave = tid >> 6;
    int4 q = *(const int4*)(cnt + blockIdx.x * 1024 + tid * 4);
    int s = q.x + q.y + q.z + q.w;
    #pragma unroll
    for (int d = 32; d > 0; d >>= 1) s += __shfl_down(s, d, 64);
    if (lane == 0) wsum[wave] = s;
    __syncthreads();
    if (tid == 0) bsum[blockIdx.x] = wsum[0] + wsum[1] + wsum[2] + wsum[3];
}

__global__ __launch_bounds__(64) void scan_bsum_k(const int* __restrict__ bsum,
                                                  int* __restrict__ boff) {
    int tid = threadIdx.x;
    int v = (tid < SCAN_NB) ? bsum[tid] : 0;
    int incl = v;
    #pragma unroll
    for (int d = 1; d < 64; d <<= 1) {
        int t = __shfl_up(incl, d, 64);
        if (tid >= d) incl += t;
    }
    if (tid < SCAN_NB) boff[tid] = incl - v;
}

__global__ __launch_bounds__(256) void scan_final_k(const int* __restrict__ cnt,
                                                    const int* __restrict__ boff,
                                                    int* __restrict__ row_ptr) {
    __shared__ int wsum[4];
    __shared__ int woff[4];
    int tid  = threadIdx.x;
    int lane = tid & 63;
    int wave = tid >> 6;
    int base = blockIdx.x * 1024 + tid * 4;
    int4 q = *(const int4*)(cnt + base);
    int s = q.x + q.y + q.z + q.w;
    int incl = s;
    #pragma unroll
    for (int d = 1; d < 64; d <<= 1) {
        int t = __shfl_up(incl, d, 64);
        if (lane >= d) incl += t;
    }
    if (lane == 63) wsum[wave] = incl;
    __syncthreads();
    if (tid == 0) {
        int run = 0;
        #pragma unroll
        for (int w = 0; w < 4; w++) { woff[w] = run; run += wsum[w]; }
    }
    __syncthreads();
    int off = boff[blockIdx.x] + woff[wave] + (incl - s);
    int4 o;
    o.x = off;
    o.y = off + q.x;
    o.z = o.y + q.y;
    o.w = o.z + q.z;
    *(int4*)(row_ptr + base) = o;
    if (blockIdx.x == 0 && tid == 0) row_ptr[N_NODES] = E_EDGES;
}

// atomic-free scatter: slot = row_ptr[row] + precomputed rank
__global__ void scatter_k(const int* __restrict__ rows, const int* __restrict__ cols,
                          const float* __restrict__ vals, const int* __restrict__ rptr,
                          const int* __restrict__ rank,
                          int* __restrict__ col_s, float* __restrict__ val_s) {
    int e = blockIdx.x * 256 + threadIdx.x;
    if (e < E_EDGES) {
        int p = rptr[rows[e]] + rank[e];
        col_s[p] = cols[e];
        val_s[p] = vals[e];
    }
}

// ---------------------------------------------------------------- GEMM fat-M
// C[M,N](bf16) = A[M,K] * Bt[N,K](bf16). r8 structure, kept: BM=256, grid 196
// blocks, 512 thr / 8 waves, single LDS buffer, 2-barrier loop. (Session
// record: five schedule/byte variants of gemm1 all land 59-63 us; this one
// is <=59 and tied-best. Pipelining attempts retired.)
// A fp32 staged via register cvt_pk into padded-72 rows; bf16 tiles via DMA
// with both-sides XOR swizzle (verified r5-r8):
//   store: source col-group (lane&7)^((lane>>3)&7)
//   read:  col slot (((kk>>3)+quad)^(lane&7))
template <bool AF32, int BM, int BN, int RW, int CW, int WM, int WN>
__global__ __launch_bounds__(512) void gemm_big(const float* __restrict__ Af,
                                                const ushort* __restrict__ Ab,
                                                const ushort* __restrict__ Bt,
                                                ushort* __restrict__ C,
                                                int M, int N, int K) {
    constexpr int BK   = 64;
    constexpr int LDTA = AF32 ? 72 : 64;        // A rows: padded (reg) / linear (DMA)
    constexpr int ACH  = (BM * BK / 8) / 512;   // fp32 path chunks per thread (4)
    __shared__ ushort As[BM * LDTA];
    __shared__ ushort Bs[BN * 64];

    const int tid  = threadIdx.x;
    const int lane = tid & 63;
    const int wave = tid >> 6;       // 0..7
    const int quad = lane >> 4;
    const int l15  = lane & 15;
    const int l7   = lane & 7;

    const int col0 = blockIdx.x * BN;
    const int row0 = blockIdx.y * BM;

    const int wr = (wave % RW) * (WM * 16);
    const int wc = (wave / RW) * (WN * 16);

    const int swz    = (l7 ^ ((lane >> 3) & 7)) << 3;  // DMA source col offset
    const int subrow = lane >> 3;                      // row within 8-row chunk

    f32x4 acc[WM][WN] = {};

    for (int k0 = 0; k0 < K; k0 += BK) {
        // ---- A tile
        if constexpr (AF32) {
            #pragma unroll
            for (int p = 0; p < ACH; p++) {
                int c = tid + p * 512;
                int row = c >> 3, sub = c & 7;
                int gr = row0 + row;
                gr = gr < M ? gr : M - 1;          // x has exactly M rows
                const float* pa = Af + (size_t)gr * K + k0 + sub * 8;
                float4 f0 = *(const float4*)pa;
                float4 f1 = *(const float4*)(pa + 4);
                uint4 q;
                q.x = pk2(f0.x, f0.y);
                q.y = pk2(f0.z, f0.w);
                q.z = pk2(f1.x, f1.y);
                q.w = pk2(f1.z, f1.w);
                *(uint4*)&As[row * LDTA + sub * 8] = q;
            }
        } else {
            // A buffer padded to gridY*BM rows: always in-bounds; garbage pad
            // rows only feed never-stored C rows (MFMA D-row independence)
            #pragma unroll
            for (int p = 0; p < BM / 64; p++) {
                int ch  = wave * (BM / 64) + p;
                int row = ch * 8 + subrow;
                gld_lds16(Ab + (size_t)(row0 + row) * K + k0 + swz, &As[ch * 512]);
            }
        }
        // ---- B tile: DMA, fire-and-forget until barrier's vmcnt drain
        #pragma unroll
        for (int p = 0; p < BN / 64; p++) {
            int ch  = wave * (BN / 64) + p;
            int row = ch * 8 + subrow;
            gld_lds16(Bt + (size_t)(col0 + row) * K + k0 + swz, &Bs[ch * 512]);
        }
        __syncthreads();
        #pragma unroll
        for (int kk = 0; kk < BK; kk += 32) {
            const int sg = ((((kk >> 3) + quad) ^ l7) << 3);  // swizzled read col
            short8 af[WM], bf[WN];
            #pragma unroll
            for (int i = 0; i < WM; i++) {
                int row = wr + i * 16 + l15;
                af[i] = AF32 ? *(const short8*)&As[row * LDTA + kk + quad * 8]
                             : *(const short8*)&As[row * 64 + sg];
            }
            #pragma unroll
            for (int j = 0; j < WN; j++) {
                int row = wc + j * 16 + l15;
                bf[j] = *(const short8*)&Bs[row * 64 + sg];
            }
            #pragma unroll
            for (int i = 0; i < WM; i++)
                #pragma unroll
                for (int j = 0; j < WN; j++)
                    acc[i][j] = __builtin_amdgcn_mfma_f32_16x16x32_bf16(af[i], bf[j], acc[i][j], 0, 0, 0);
        }
        __syncthreads();
    }

    // epilogue: C/D layout col=lane&15, row=quad*4+reg
    #pragma unroll
    for (int i = 0; i < WM; i++)
        #pragma unroll
        for (int j = 0; j < WN; j++)
            #pragma unroll
            for (int rr = 0; rr < 4; rr++) {
                int grow = row0 + wr + i * 16 + quad * 4 + rr;
                int gcol = col0 + wc + j * 16 + l15;
                if (grow < M) C[(size_t)grow * N + gcol] = f2bf(acc[i][j][rr]);
            }
}

// ---------------------------------------------------------------- SpMM 1
// wave per row. NEW (r9): 16 B/lane, TWO edges per wave-instruction:
//   half = lane>>5 selects the edge of a pair; li = lane&31 covers dims
//   [li*8, li*8+8). Gather instrs/edge halved (was 8 B/lane, 1 edge/instr);
//   2 pairs unrolled -> 8 edges in flight. Half-combine = one shfl_xor(32).
__global__ __launch_bounds__(256) void spmm1_k(const int* __restrict__ row_ptr,
                                               const int* __restrict__ col_s,
                                               const float* __restrict__ val_s,
                                               const ushort* __restrict__ h0,
                                               const float* __restrict__ b1,
                                               ushort* __restrict__ h) {
    int wave = threadIdx.x >> 6;
    int lane = threadIdx.x & 63;
    int r = blockIdx.x * 4 + wave;
    if (r >= N_NODES) return;
    int s = row_ptr[r];
    int e = row_ptr[r + 1];
    const int half = lane >> 5;   // which edge of the pair
    const int li   = lane & 31;   // dim group: dims [li*8, li*8+8)
    const ushort* hp = h0 + li * 8;
    float a0 = 0.f, a1 = 0.f, a2 = 0.f, a3 = 0.f;
    float a4 = 0.f, a5 = 0.f, a6 = 0.f, a7 = 0.f;
    int i = s;
    // main: 2 pairs (4 edges) per iteration, 2 independent gathers per lane
    for (; i + 4 <= e; i += 4) {
        int   c0 = col_s[i + half];
        float v0 = val_s[i + half];
        int   c1 = col_s[i + 2 + half];
        float v1 = val_s[i + 2 + half];
        short8 q0 = *(const short8*)(hp + (size_t)c0 * HID);
        short8 q1 = *(const short8*)(hp + (size_t)c1 * HID);
        a0 += v0 * bf2f((ushort)q0[0]); a1 += v0 * bf2f((ushort)q0[1]);
        a2 += v0 * bf2f((ushort)q0[2]); a3 += v0 * bf2f((ushort)q0[3]);
        a4 += v0 * bf2f((ushort)q0[4]); a5 += v0 * bf2f((ushort)q0[5]);
        a6 += v0 * bf2f((ushort)q0[6]); a7 += v0 * bf2f((ushort)q0[7]);
        a0 += v1 * bf2f((ushort)q1[0]); a1 += v1 * bf2f((ushort)q1[1]);
        a2 += v1 * bf2f((ushort)q1[2]); a3 += v1 * bf2f((ushort)q1[3]);
        a4 += v1 * bf2f((ushort)q1[4]); a5 += v1 * bf2f((ushort)q1[5]);
        a6 += v1 * bf2f((ushort)q1[6]); a7 += v1 * bf2f((ushort)q1[7]);
    }
    // one remaining pair
    for (; i + 2 <= e; i += 2) {
        int   c = col_s[i + half];
        float v = val_s[i + half];
        short8 q = *(const short8*)(hp + (size_t)c * HID);
        a0 += v * bf2f((ushort)q[0]); a1 += v * bf2f((ushort)q[1]);
        a2 += v * bf2f((ushort)q[2]); a3 += v * bf2f((ushort)q[3]);
        a4 += v * bf2f((ushort)q[4]); a5 += v * bf2f((ushort)q[5]);
        a6 += v * bf2f((ushort)q[6]); a7 += v * bf2f((ushort)q[7]);
    }
    // single tail edge: processed by half==0 lanes only (full dim coverage)
    if (i < e && half == 0) {
        int   c = col_s[i];
        float v = val_s[i];
        short8 q = *(const short8*)(hp + (size_t)c * HID);
        a0 += v * bf2f((ushort)q[0]); a1 += v * bf2f((ushort)q[1]);
        a2 += v * bf2f((ushort)q[2]); a3 += v * bf2f((ushort)q[3]);
        a4 += v * bf2f((ushort)q[4]); a5 += v * bf2f((ushort)q[5]);
        a6 += v * bf2f((ushort)q[6]); a7 += v * bf2f((ushort)q[7]);
    }
    // combine the two halves (lane l <-> l^32 hold same dims)
    a0 += __shfl_xor(a0, 32, 64); a1 += __shfl_xor(a1, 32, 64);
    a2 += __shfl_xor(a2, 32, 64); a3 += __shfl_xor(a3, 32, 64);
    a4 += __shfl_xor(a4, 32, 64); a5 += __shfl_xor(a5, 32, 64);
    a6 += __shfl_xor(a6, 32, 64); a7 += __shfl_xor(a7, 32, 64);
    if (half == 0) {
        float4 bb0 = *(const float4*)(b1 + li * 8);
        float4 bb1 = *(const float4*)(b1 + li * 8 + 4);
        a0 = fmaxf(a0 + bb0.x, 0.f); a1 = fmaxf(a1 + bb0.y, 0.f);
        a2 = fmaxf(a2 + bb0.z, 0.f); a3 = fmaxf(a3 + bb0.w, 0.f);
        a4 = fmaxf(a4 + bb1.x, 0.f); a5 = fmaxf(a5 + bb1.y, 0.f);
        a6 = fmaxf(a6 + bb1.z, 0.f); a7 = fmaxf(a7 + bb1.w, 0.f);
        short8 o;
        o[0] = (short)f2bf(a0); o[1] = (short)f2bf(a1);
        o[2] = (short)f2bf(a2); o[3] = (short)f2bf(a3);
        o[4] = (short)f2bf(a4); o[5] = (short)f2bf(a5);
        o[6] = (short)f2bf(a6); o[7] = (short)f2bf(a7);
        *(short8*)(h + (size_t)r * HID + li * 8) = o;
    }
}

// ---------------------------------------------------------------- SpMM 2
// wave per row. NEW (r9): 8 edge-slots per wave (slot = lane>>3), 16 B/lane,
// li = lane&7 covers dims [li*8, li*8+8). Reduce over slot bits {8,16,32}.
__global__ __launch_bounds__(256) void spmm2_k(const int* __restrict__ row_ptr,
                                               const int* __restrict__ col_s,
                                               const float* __restrict__ val_s,
                                               const ushort* __restrict__ h2,
                                               const float* __restrict__ b2,
                                               float* __restrict__ out) {
    int wave = threadIdx.x >> 6;
    int lane = threadIdx.x & 63;
    int r = blockIdx.x * 4 + wave;
    if (r >= N_NODES) return;
    int s = row_ptr[r];
    int e = row_ptr[r + 1];
    int slot = lane >> 3;   // 0..7: edge slot
    int li   = lane & 7;    // dim group: dims [li*8, li*8+8)
    float a0 = 0.f, a1 = 0.f, a2 = 0.f, a3 = 0.f;
    float a4 = 0.f, a5 = 0.f, a6 = 0.f, a7 = 0.f;
    const ushort* hp = h2 + (size_t)li * 8;
    for (int i = s + slot; i < e; i += 8) {
        int   c = col_s[i];
        float v = val_s[i];
        short8 q = *(const short8*)(hp + (size_t)c * OUTD);
        a0 += v * bf2f((ushort)q[0]); a1 += v * bf2f((ushort)q[1]);
        a2 += v * bf2f((ushort)q[2]); a3 += v * bf2f((ushort)q[3]);
        a4 += v * bf2f((ushort)q[4]); a5 += v * bf2f((ushort)q[5]);
        a6 += v * bf2f((ushort)q[6]); a7 += v * bf2f((ushort)q[7]);
    }
    #pragma unroll
    for (int m = 8; m < 64; m <<= 1) {
        a0 += __shfl_xor(a0, m, 64); a1 += __shfl_xor(a1, m, 64);
        a2 += __shfl_xor(a2, m, 64); a3 += __shfl_xor(a3, m, 64);
        a4 += __shfl_xor(a4, m, 64); a5 += __shfl_xor(a5, m, 64);
        a6 += __shfl_xor(a6, m, 64); a7 += __shfl_xor(a7, m, 64);
    }
    if (slot == 0) {
        float4 bb0 = *(const float4*)(b2 + li * 8);
        float4 bb1 = *(const float4*)(b2 + li * 8 + 4);
        float4 o0, o1;
        o0.x = a0 + bb0.x; o0.y = a1 + bb0.y; o0.z = a2 + bb0.z; o0.w = a3 + bb0.w;
        o1.x = a4 + bb1.x; o1.y = a5 + bb1.y; o1.z = a6 + bb1.z; o1.w = a7 + bb1.w;
        *(float4*)(out + (size_t)r * OUTD + li * 8)     = o0;
        *(float4*)(out + (size_t)r * OUTD + li * 8 + 4) = o1;
    }
}

// ---------------------------------------------------------------- launch
extern "C" void kernel_launch(void* const* d_in, const int* in_sizes, int n_in,
                              void* d_out, int out_size, void* d_ws, size_t ws_size,
                              hipStream_t stream) {
    const float* x    = (const float*)d_in[0];
    const int*   rows = (const int*)d_in[1];
    const int*   cols = (const int*)d_in[2];
    const float* vals = (const float*)d_in[3];
    const float* W1   = (const float*)d_in[4];
    const float* b1   = (const float*)d_in[5];
    const float* W2   = (const float*)d_in[6];
    const float* b2   = (const float*)d_in[7];
    float* out = (float*)d_out;

    char* ws = (char*)d_ws;
    size_t off = 0;
    auto alloc = [&](size_t bytes) {
        char* p = ws + off;
        off = (off + bytes + 255) & ~(size_t)255;
        return p;
    };
    ushort* w1t   = (ushort*)alloc((size_t)HID * IN_DIM * 2);
    ushort* w2t   = (ushort*)alloc((size_t)OUTD * HID * 2);
    ushort* h0    = (ushort*)alloc((size_t)N_NODES * HID * 2);
    ushort* h     = (ushort*)alloc((size_t)MP_BIG * HID * 2);    // padded rows (DMA in-bounds)
    ushort* h2    = (ushort*)alloc((size_t)N_NODES * OUTD * 2);
    int*    cnt   = (int*)alloc((PAD_N) * 4);
    int*    rptr  = (int*)alloc((PAD_N + 1) * 4);
    int*    bsum  = (int*)alloc(SCAN_NB * 4);
    int*    boff  = (int*)alloc(SCAN_NB * 4);
    int*    rank  = (int*)alloc((size_t)E_EDGES * 4);
    int*    col_s = (int*)alloc((size_t)E_EDGES * 4);
    float*  val_s = (float*)alloc((size_t)E_EDGES * 4);

    // init: zero cnt + weight transpose/convert (fused, independent work)
    {
        const int work = IN_DIM * HID + HID * OUTD;  // 147456 > PAD_N
        init_k<<<(work + 255) / 256, 256, 0, stream>>>(W1, W2, w1t, w2t, cnt);
    }
    // CSR build (reused by both SpMMs)
    hist_k<<<(E_EDGES + 255) / 256, 256, 0, stream>>>(rows, cnt, rank);
    scan_part_k<<<SCAN_NB, 256, 0, stream>>>(cnt, bsum);
    scan_bsum_k<<<1, 64, 0, stream>>>(bsum, boff);
    scan_final_k<<<SCAN_NB, 256, 0, stream>>>(cnt, boff, rptr);
    scatter_k<<<(E_EDGES + 255) / 256, 256, 0, stream>>>(rows, cols, vals, rptr, rank, col_s, val_s);

    // layer 1: h0 = x @ W1. Fat tile 256x256, grid 1x196
    gemm_big<true, 256, 256, 4, 2, 4, 8><<<dim3(HID / 256, MP_BIG / 256), 512, 0, stream>>>(
        x, nullptr, w1t, h0, N_NODES, HID, IN_DIM);
    spmm1_k<<<(N_NODES + 3) / 4, 256, 0, stream>>>(rptr, col_s, val_s, h0, b1, h);

    // layer 2: fat tile 256x64, all-DMA
    gemm_big<false, 256, 64, 8, 1, 2, 4><<<dim3(OUTD / 64, MP_BIG / 256), 512, 0, stream>>>(
        nullptr, h, w2t, h2, N_NODES, OUTD, HID);
    spmm2_k<<<(N_NODES + 3) / 4, 256, 0, stream>>>(rptr, col_s, val_s, h2, b2, out);
}